// Round 6
// baseline (459.381 us; speedup 1.0000x reference)
//
#include <hip/hip_runtime.h>
#include <hip/hip_cooperative_groups.h>

namespace cg = cooperative_groups;

#define NPTS 8192
#define DIM  128
#define NCLS 64
#define NT   64
#define NTILES (NT * (NT + 1) / 2)   // 2080 triangular tiles
#define NBLK  1024                   // 4 blocks/CU x 256 CU, exactly co-resident
#define FEPS 1e-16f
#define L2E  1.442695041f

// ws layout (float elements). Kernels init all state (no host memset).
#define WS_S     0          // 8192 floats: S_i (sorted order)
#define WS_CNT   8192       // 64 ints
#define WS_LOSS  8256       // 1 float
#define WS_DONE  8257       // 1 uint
#define WS_SQ    8258       // 8192 floats (sorted order)
#define WS_OFFS  16450      // 64 ints: class start offsets
#define WS_LABS  24642      // 8192 ints: sorted-order labels
#define WS_G16A  32836      // 16B aligned; 1MB fp8 = 262144 floats
#define WS_DP    294980     // fixed-stride dpair: class c at (c<<16), row stride 256

typedef float f32x4 __attribute__((ext_vector_type(4)));

__device__ inline float fast_sqrt(float x) {
    float r;
    asm("v_sqrt_f32 %0, %1" : "=v"(r) : "v"(x));
    return r;
}

// anti-diagonal tile decode: all tiles with distance d=jt-bt precede d+1.
__device__ inline void tile_decode(int p, int& bt, int& jt) {
    int d = (int)((129.0f - fast_sqrt((float)(16641 - 8 * p))) * 0.5f);
    if (d < 0) d = 0; if (d > 63) d = 63;
    while (d > 0 && (d * 64 - ((d * (d - 1)) >> 1)) > p) --d;
    while (((d + 1) * 64 - (((d + 1) * d) >> 1)) <= p) ++d;
    bt = p - (d * 64 - ((d * (d - 1)) >> 1));
    jt = bt + d;
}

// stage one (A,B) tile pair into LDS base (4 waves x 4KB steps, 16B/lane)
#define STAGE_TILES(BT, JT, LDSB) do {                                                      \
    const unsigned char* gA_ = Gb + (size_t)(BT) * 16384;                                   \
    const unsigned char* gB_ = Gb + (size_t)(JT) * 16384;                                   \
    const int wb_ = w << 10, lb_ = lane << 4;                                               \
    _Pragma("unroll")                                                                       \
    for (int k_ = 0; k_ < 4; ++k_) {                                                        \
        __builtin_amdgcn_global_load_lds(                                                   \
            (const __attribute__((address_space(1))) unsigned int*)(gA_ + (k_ << 12) + wb_ + lb_), \
            (__attribute__((address_space(3))) unsigned int*)((LDSB) + (k_ << 12) + wb_),   \
            16, 0, 0);                                                                      \
        __builtin_amdgcn_global_load_lds(                                                   \
            (const __attribute__((address_space(1))) unsigned int*)(gB_ + (k_ << 12) + wb_ + lb_), \
            (__attribute__((address_space(3))) unsigned int*)((LDSB) + 16384 + (k_ << 12) + wb_),  \
            16, 0, 0);                                                                      \
    }                                                                                       \
} while (0)

// LDS phase overlays
struct P1 { int llab[NPTS]; int plist[256]; int wsum[4]; int wless[4]; };   // 33.0 KB
struct P2 { unsigned char ldsG[32768]; float sqi[2][128]; float sqj[2][128];
            int lli[2][128]; int llj[2][128]; int s_offs[NCLS]; };          // 36.3 KB
struct P3 { float Sg[256]; float redf[4]; };

// =====================================================================
// MEGA: all three phases in one cooperative kernel (grid = 1024 x 256).
// Phase 1: bucket + fp8 prep (16 blocks/class). Phase 2: persistent
// triangular N^2 pass (round-5 body). Phase 3: per-class loss
// (16 blocks/class, 64 row-streams). Grid syncs + device fences between.
// =====================================================================
__global__ void __launch_bounds__(256, 4)
mega_kernel(const int* __restrict__ labels,
            const float* __restrict__ feat,
            int* __restrict__ cnt,
            int* __restrict__ offs,
            float* __restrict__ sq,
            unsigned char* __restrict__ Gb,
            float* __restrict__ S,
            int* __restrict__ labs,
            float* __restrict__ loss_sum,
            unsigned int* __restrict__ done,
            float* __restrict__ dpair,
            float* __restrict__ out) {
    __shared__ __align__(16) union { P1 p1; P2 p2; P3 p3; } u;

    const int tid = threadIdx.x;
    const int bid = blockIdx.x;
    const int w = tid >> 6, lane = tid & 63;
    cg::grid_group grid = cg::this_grid();

    // ---------------- phase 1: bucket + prep ----------------
    {
        const int c = bid >> 4, six = bid & 15;   // 16 blocks per class

        {
            const uint4* L4 = (const uint4*)labels;
            uint4* S4 = (uint4*)u.p1.llab;
#pragma unroll
            for (int k = 0; k < 8; ++k) S4[k * 256 + tid] = L4[k * 256 + tid];
        }
        if (bid == 0 && tid == 0) { loss_sum[0] = 0.0f; done[0] = 0u; }
        __syncthreads();

        int ce = 0, clt = 0;
#pragma unroll
        for (int k = 0; k < 32; ++k) {
            int l = u.p1.llab[tid + 256 * k];
            ce += (l == c) ? 1 : 0;
            clt += (l < c) ? 1 : 0;
        }
        int incl = ce;
#pragma unroll
        for (int o = 1; o < 64; o <<= 1) {
            int t1 = __shfl_up(incl, o, 64);
            if (lane >= o) incl += t1;
        }
        if (lane == 63) u.p1.wsum[w] = incl;
        int t = clt;
#pragma unroll
        for (int o = 1; o < 64; o <<= 1) t += __shfl_xor(t, o, 64);
        if (lane == 0) u.p1.wless[w] = t;
        __syncthreads();

        int wpre = 0;
#pragma unroll
        for (int ww = 0; ww < 4; ++ww) if (ww < w) wpre += u.p1.wsum[ww];
        const int offc = u.p1.wless[0] + u.p1.wless[1] + u.p1.wless[2] + u.p1.wless[3];
        const int n = u.p1.wsum[0] + u.p1.wsum[1] + u.p1.wsum[2] + u.p1.wsum[3];

        int r = wpre + incl - ce;                 // LOCAL index within class
#pragma unroll
        for (int k = 0; k < 32; ++k) {
            int idx = tid + 256 * k;
            if (u.p1.llab[idx] == c) { u.p1.plist[r] = idx; ++r; }
        }
        if (six == 0 && tid == 0) { cnt[c] = n; offs[c] = offc; }
        __syncthreads();   // plist visible

        const int lo = (n * six) >> 4;
        const int hi = (n * (six + 1)) >> 4;

        for (int m = lo + tid; m < hi; m += 256) { S[offc + m] = 0.0f; labs[offc + m] = c; }

        const int kl = lane & 31;
        const int rloc = lane >> 5;
        for (int base = lo; base < hi; base += 8) {
            int m = base + w * 2 + rloc;
            if (m < hi) {
                int i = u.p1.plist[m];
                int sp = offc + m;
                float4 v = ((const float4*)(feat + (size_t)i * DIM))[kl];
                unsigned lo8 = (unsigned)__builtin_amdgcn_cvt_pk_fp8_f32(v.x, v.y, 0, false) & 0xffffu;
                unsigned hi8 = (unsigned)__builtin_amdgcn_cvt_pk_fp8_f32(v.z, v.w, 0, false);
                unsigned word = lo8 | (hi8 << 16);
                int tt = sp >> 7, mm = sp & 127;
                int cc = kl >> 1, pos = (kl & 1) * 4;
                *(unsigned*)&Gb[(size_t)tt * 16384 + cc * 1024 + mm * 8 + pos] = word;
                float s = v.x * v.x + v.y * v.y + v.z * v.z + v.w * v.w;
#pragma unroll
                for (int msk = 1; msk <= 16; msk <<= 1) s += __shfl_xor(s, msk, 64);
                if (kl == 0) sq[sp] = s;
            }
        }
    }

    __threadfence();
    grid.sync();

    // ---------------- phase 2: persistent triangular N^2 ----------------
    {
        const int b = bid;
        int tp0 = b, tp1 = NBLK + b, tp2 = -1;
        int nt = 2;
        if (b >= NBLK - 32) { tp2 = 2048 + (NBLK - 1 - b); nt = 3; }

        unsigned char* ldsG = u.p2.ldsG;
        float (&sqi)[2][128] = u.p2.sqi;
        float (&sqj)[2][128] = u.p2.sqj;
        int (&lli)[2][128] = u.p2.lli;
        int (&llj)[2][128] = u.p2.llj;
        int (&s_offs)[NCLS] = u.p2.s_offs;

        const int wr = w >> 1, wc = w & 1;
        const int q = lane >> 4, ml = lane & 15;

        int bt, jt;
        tile_decode(tp0, bt, jt);

        STAGE_TILES(bt, jt, ldsG);
        if (tid < 128) {
            sqi[0][tid] = sq[bt * 128 + tid]; lli[0][tid] = labs[bt * 128 + tid];
        } else {
            sqj[0][tid - 128] = sq[jt * 128 + tid - 128];
            llj[0][tid - 128] = labs[jt * 128 + tid - 128];
        }
        if (w == 0) s_offs[lane] = offs[lane];
        __syncthreads();   // staging vmcnt + meta + offs

        const long* A8 = (const long*)ldsG;
        const long* B8 = (const long*)(ldsG + 16384);

        for (int it = 0; it < nt; ++it) {
            const int cur = it & 1;
            const int ib = bt * 128, jb = jt * 128;
            const bool diag = (bt == jt);
            const bool boundary = diag || (lli[cur][127] == llj[cur][0]);

            f32x4 acc[4][4];
#pragma unroll
            for (int a = 0; a < 4; ++a)
#pragma unroll
                for (int bb = 0; bb < 4; ++bb) acc[a][bb] = (f32x4){0.f, 0.f, 0.f, 0.f};

#pragma unroll
            for (int s = 0; s < 4; ++s) {
                long af[4], bf[4];
                int kbase = (s * 4 + q) * 128;
#pragma unroll
                for (int ii = 0; ii < 4; ++ii) af[ii] = A8[kbase + wr * 64 + ii * 16 + ml];
#pragma unroll
                for (int jj = 0; jj < 4; ++jj) bf[jj] = B8[kbase + wc * 64 + jj * 16 + ml];
#pragma unroll
                for (int ii = 0; ii < 4; ++ii)
#pragma unroll
                    for (int jj = 0; jj < 4; ++jj)
                        acc[ii][jj] = __builtin_amdgcn_mfma_f32_16x16x32_fp8_fp8(af[ii], bf[jj], acc[ii][jj], 0, 0, 0);
            }

            __syncthreads();   // all ldsG reads done -> buffer reusable

            int btn = bt, jtn = jt;
            if (it + 1 < nt) {   // stage next tile; latency hides under epilogue
                int pn = (it + 1 == 1) ? tp1 : tp2;
                tile_decode(pn, btn, jtn);
                STAGE_TILES(btn, jtn, ldsG);
                const int nb = cur ^ 1;
                if (tid < 128) {
                    sqi[nb][tid] = sq[btn * 128 + tid]; lli[nb][tid] = labs[btn * 128 + tid];
                } else {
                    sqj[nb][tid - 128] = sq[jtn * 128 + tid - 128];
                    llj[nb][tid - 128] = labs[jtn * 128 + tid - 128];
                }
            }

            // ---- epilogue for tile it (meta buffer cur) ----
            int cl[4]; float sj[4];
#pragma unroll
            for (int jj = 0; jj < 4; ++jj) {
                cl[jj] = wc * 64 + jj * 16 + ml;
                sj[jj] = sqj[cur][cl[jj]];
            }
            float rs[4][4];
#pragma unroll
            for (int a = 0; a < 4; ++a)
#pragma unroll
                for (int r = 0; r < 4; ++r) rs[a][r] = 0.0f;
            float colsum[4] = {0.f, 0.f, 0.f, 0.f};

            if (!boundary) {
#pragma unroll
                for (int ii = 0; ii < 4; ++ii) {
                    int rl = wr * 64 + ii * 16 + q * 4;
                    float si4[4];
#pragma unroll
                    for (int r = 0; r < 4; ++r) si4[r] = sqi[cur][rl + r];
#pragma unroll
                    for (int jj = 0; jj < 4; ++jj)
#pragma unroll
                        for (int r = 0; r < 4; ++r) {
                            float d2 = fmaf(-2.0f, acc[ii][jj][r], si4[r] + sj[jj]);
                            float dd = fast_sqrt(fmaxf(d2, FEPS));
                            float e = exp2f(fmaf(dd, -L2E, L2E));
                            rs[ii][r] += e;
                            colsum[jj] += e;
                        }
                }
            } else {
                int lcj[4];
#pragma unroll
                for (int jj = 0; jj < 4; ++jj) lcj[jj] = llj[cur][cl[jj]];
#pragma unroll
                for (int ii = 0; ii < 4; ++ii) {
                    int rl = wr * 64 + ii * 16 + q * 4;
                    int lri[4]; float si4[4];
#pragma unroll
                    for (int r = 0; r < 4; ++r) { lri[r] = lli[cur][rl + r]; si4[r] = sqi[cur][rl + r]; }
#pragma unroll
                    for (int jj = 0; jj < 4; ++jj)
#pragma unroll
                        for (int r = 0; r < 4; ++r) {
                            float d2 = fmaf(-2.0f, acc[ii][jj][r], si4[r] + sj[jj]);
                            float dd = fast_sqrt(fmaxf(d2, FEPS));
                            float e = exp2f(fmaf(dd, -L2E, L2E));
                            bool same = (lri[r] == lcj[jj]);
                            float ep = same ? 0.0f : e;
                            rs[ii][r] += ep;
                            colsum[jj] += ep;
                            if (same) {
                                int c2 = lri[r];
                                int offv = s_offs[c2];
                                int ra = ib + rl + r - offv;
                                int rb = jb + cl[jj] - offv;
                                if (ra < rb)
                                    dpair[(c2 << 16) + (ra << 8) + rb] = dd;
                            }
                        }
                }
            }

            // hoisted reduces: 16 independent depth-4 chains, pipelined
#pragma unroll
            for (int m = 1; m < 16; m <<= 1)
#pragma unroll
                for (int ii = 0; ii < 4; ++ii)
#pragma unroll
                    for (int r = 0; r < 4; ++r) rs[ii][r] += __shfl_xor(rs[ii][r], m, 64);
            if (ml == 0) {
#pragma unroll
                for (int ii = 0; ii < 4; ++ii) {
                    int rl = wr * 64 + ii * 16 + q * 4;
#pragma unroll
                    for (int r = 0; r < 4; ++r) atomicAdd(&S[ib + rl + r], rs[ii][r]);
                }
            }
            if (!diag) {
#pragma unroll
                for (int m = 16; m < 64; m <<= 1)
#pragma unroll
                    for (int jj = 0; jj < 4; ++jj) colsum[jj] += __shfl_xor(colsum[jj], m, 64);
                if (q == 0) {
#pragma unroll
                    for (int jj = 0; jj < 4; ++jj)
                        atomicAdd(&S[jb + cl[jj]], colsum[jj]);
                }
            }

            if (it + 1 < nt) __syncthreads();   // next tile staged + meta visible
            bt = btn; jt = jtn;
        }
    }

    __threadfence();
    grid.sync();

    // ---------------- phase 3: per-class loss ----------------
    {
        const int c = bid >> 4, q16 = bid & 15;   // 16 blocks/class, 64 row-streams
        const int n = cnt[c];
        const int off = offs[c];
        const float* dbase = dpair + (c << 16);

        for (int m_ = tid; m_ < n; m_ += 256) u.p3.Sg[m_] = S[off + m_];
        __syncthreads();

        float total = 0.f;
        for (int a = q16 * 4 + w; a < n; a += 64) {
            float Sa = u.p3.Sg[a];
            const float* drow = dbase + (a << 8);
            for (int bb = lane; bb < n; bb += 64) {
                if (bb > a) {
                    float J = __logf(Sa + u.p3.Sg[bb]) + drow[bb];
                    float h = fmaxf(J, 0.0f);
                    total += 2.0f * h * h;
                }
            }
            if (lane == 0) {                       // diagonal: d = sqrt(EPS)
                float J = __logf(2.0f * Sa) + 1e-8f;
                float h = fmaxf(J, 0.0f);
                total += h * h;
            }
        }
#pragma unroll
        for (int off2 = 32; off2 > 0; off2 >>= 1) total += __shfl_down(total, off2, 64);
        if (lane == 0) u.p3.redf[w] = total;

        int tot2 = 0;
        if (w == 0) {
            int v = cnt[lane];
            tot2 = v * v;
#pragma unroll
            for (int o = 1; o < 64; o <<= 1) tot2 += __shfl_xor(tot2, o, 64);
        }
        __syncthreads();
        if (tid == 0) {
            atomicAdd(loss_sum, u.p3.redf[0] + u.p3.redf[1] + u.p3.redf[2] + u.p3.redf[3]);
            __threadfence();
            unsigned int t = atomicAdd(done, 1u);
            if (t == gridDim.x - 1) {
                float tot = atomicAdd(loss_sum, 0.0f);
                out[0] = tot / (2.0f * (float)tot2);
            }
        }
    }
}

// =====================================================================
// Fallback path (3 separate kernels) in case cooperative launch fails.
// =====================================================================
__global__ void bucket_prep_kernel(const int* __restrict__ labels,
                                   const float* __restrict__ feat,
                                   int* __restrict__ cnt,
                                   int* __restrict__ offs,
                                   float* __restrict__ sq,
                                   unsigned char* __restrict__ G,
                                   float* __restrict__ S,
                                   int* __restrict__ labs,
                                   float* __restrict__ loss_sum,
                                   unsigned int* __restrict__ done) {
    __shared__ int llab[NPTS];
    __shared__ int plist[256];
    __shared__ int wsum[4], wless[4];
    const int tid = threadIdx.x;
    const int w = tid >> 6, lane = tid & 63;
    const int c = blockIdx.x >> 1, half = blockIdx.x & 1;

    {
        const uint4* L4 = (const uint4*)labels;
        uint4* S4 = (uint4*)llab;
#pragma unroll
        for (int k = 0; k < 8; ++k) S4[k * 256 + tid] = L4[k * 256 + tid];
    }
    if (blockIdx.x == 0 && tid == 0) { loss_sum[0] = 0.0f; done[0] = 0u; }
    __syncthreads();

    int ce = 0, clt = 0;
#pragma unroll
    for (int k = 0; k < 32; ++k) {
        int l = llab[tid + 256 * k];
        ce += (l == c) ? 1 : 0;
        clt += (l < c) ? 1 : 0;
    }
    int incl = ce;
#pragma unroll
    for (int o = 1; o < 64; o <<= 1) {
        int t1 = __shfl_up(incl, o, 64);
        if (lane >= o) incl += t1;
    }
    if (lane == 63) wsum[w] = incl;
    int t = clt;
#pragma unroll
    for (int o = 1; o < 64; o <<= 1) t += __shfl_xor(t, o, 64);
    if (lane == 0) wless[w] = t;
    __syncthreads();

    int wpre = 0;
#pragma unroll
    for (int ww = 0; ww < 4; ++ww) if (ww < w) wpre += wsum[ww];
    const int offc = wless[0] + wless[1] + wless[2] + wless[3];
    const int n = wsum[0] + wsum[1] + wsum[2] + wsum[3];

    int r = wpre + incl - ce;
#pragma unroll
    for (int k = 0; k < 32; ++k) {
        int idx = tid + 256 * k;
        if (llab[idx] == c) { plist[r] = idx; ++r; }
    }
    if (half == 0 && tid == 0) { cnt[c] = n; offs[c] = offc; }
    __syncthreads();

    const int mid = (n + 1) >> 1;
    const int lo = half ? mid : 0;
    const int hi = half ? n : mid;

    for (int m = lo + tid; m < hi; m += 256) { S[offc + m] = 0.0f; labs[offc + m] = c; }

    const int kl = lane & 31;
    const int rloc = lane >> 5;
    for (int base = lo; base < hi; base += 8) {
        int m = base + w * 2 + rloc;
        if (m < hi) {
            int i = plist[m];
            int sp = offc + m;
            float4 v = ((const float4*)(feat + (size_t)i * DIM))[kl];
            unsigned lo8 = (unsigned)__builtin_amdgcn_cvt_pk_fp8_f32(v.x, v.y, 0, false) & 0xffffu;
            unsigned hi8 = (unsigned)__builtin_amdgcn_cvt_pk_fp8_f32(v.z, v.w, 0, false);
            unsigned word = lo8 | (hi8 << 16);
            int tt = sp >> 7, mm = sp & 127;
            int cc = kl >> 1, pos = (kl & 1) * 4;
            *(unsigned*)&G[(size_t)tt * 16384 + cc * 1024 + mm * 8 + pos] = word;
            float s = v.x * v.x + v.y * v.y + v.z * v.z + v.w * v.w;
#pragma unroll
            for (int msk = 1; msk <= 16; msk <<= 1) s += __shfl_xor(s, msk, 64);
            if (kl == 0) sq[sp] = s;
        }
    }
}

__launch_bounds__(256, 4)
__global__ void gemm_S(const unsigned char* __restrict__ Gb,
                       const float* __restrict__ sq,
                       const int* __restrict__ labs,
                       const int* __restrict__ offs,
                       float* __restrict__ S,
                       float* __restrict__ dpair) {
    const int b = blockIdx.x;
    int tp0 = b, tp1 = NBLK + b, tp2 = -1;
    int nt = 2;
    if (b >= NBLK - 32) { tp2 = 2048 + (NBLK - 1 - b); nt = 3; }

    __shared__ __align__(16) unsigned char ldsG[32768];
    __shared__ float sqi[2][128], sqj[2][128];
    __shared__ int lli[2][128], llj[2][128];
    __shared__ int s_offs[NCLS];

    const int tid = threadIdx.x;
    const int w = tid >> 6, lane = tid & 63;
    const int wr = w >> 1, wc = w & 1;
    const int q = lane >> 4, ml = lane & 15;

    int bt, jt;
    tile_decode(tp0, bt, jt);
    STAGE_TILES(bt, jt, ldsG);
    if (tid < 128) {
        sqi[0][tid] = sq[bt * 128 + tid]; lli[0][tid] = labs[bt * 128 + tid];
    } else {
        sqj[0][tid - 128] = sq[jt * 128 + tid - 128];
        llj[0][tid - 128] = labs[jt * 128 + tid - 128];
    }
    if (w == 0) s_offs[lane] = offs[lane];
    __syncthreads();

    const long* A8 = (const long*)ldsG;
    const long* B8 = (const long*)(ldsG + 16384);

    for (int it = 0; it < nt; ++it) {
        const int cur = it & 1;
        const int ib = bt * 128, jb = jt * 128;
        const bool diag = (bt == jt);
        const bool boundary = diag || (lli[cur][127] == llj[cur][0]);

        f32x4 acc[4][4];
#pragma unroll
        for (int a = 0; a < 4; ++a)
#pragma unroll
            for (int bb = 0; bb < 4; ++bb) acc[a][bb] = (f32x4){0.f, 0.f, 0.f, 0.f};

#pragma unroll
        for (int s = 0; s < 4; ++s) {
            long af[4], bf[4];
            int kbase = (s * 4 + q) * 128;
#pragma unroll
            for (int ii = 0; ii < 4; ++ii) af[ii] = A8[kbase + wr * 64 + ii * 16 + ml];
#pragma unroll
            for (int jj = 0; jj < 4; ++jj) bf[jj] = B8[kbase + wc * 64 + jj * 16 + ml];
#pragma unroll
            for (int ii = 0; ii < 4; ++ii)
#pragma unroll
                for (int jj = 0; jj < 4; ++jj)
                    acc[ii][jj] = __builtin_amdgcn_mfma_f32_16x16x32_fp8_fp8(af[ii], bf[jj], acc[ii][jj], 0, 0, 0);
        }

        __syncthreads();

        int btn = bt, jtn = jt;
        if (it + 1 < nt) {
            int pn = (it + 1 == 1) ? tp1 : tp2;
            tile_decode(pn, btn, jtn);
            STAGE_TILES(btn, jtn, ldsG);
            const int nb = cur ^ 1;
            if (tid < 128) {
                sqi[nb][tid] = sq[btn * 128 + tid]; lli[nb][tid] = labs[btn * 128 + tid];
            } else {
                sqj[nb][tid - 128] = sq[jtn * 128 + tid - 128];
                llj[nb][tid - 128] = labs[jtn * 128 + tid - 128];
            }
        }

        int cl[4]; float sj[4];
#pragma unroll
        for (int jj = 0; jj < 4; ++jj) {
            cl[jj] = wc * 64 + jj * 16 + ml;
            sj[jj] = sqj[cur][cl[jj]];
        }
        float rs[4][4];
#pragma unroll
        for (int a = 0; a < 4; ++a)
#pragma unroll
            for (int r = 0; r < 4; ++r) rs[a][r] = 0.0f;
        float colsum[4] = {0.f, 0.f, 0.f, 0.f};

        if (!boundary) {
#pragma unroll
            for (int ii = 0; ii < 4; ++ii) {
                int rl = wr * 64 + ii * 16 + q * 4;
                float si4[4];
#pragma unroll
                for (int r = 0; r < 4; ++r) si4[r] = sqi[cur][rl + r];
#pragma unroll
                for (int jj = 0; jj < 4; ++jj)
#pragma unroll
                    for (int r = 0; r < 4; ++r) {
                        float d2 = fmaf(-2.0f, acc[ii][jj][r], si4[r] + sj[jj]);
                        float dd = fast_sqrt(fmaxf(d2, FEPS));
                        float e = exp2f(fmaf(dd, -L2E, L2E));
                        rs[ii][r] += e;
                        colsum[jj] += e;
                    }
            }
        } else {
            int lcj[4];
#pragma unroll
            for (int jj = 0; jj < 4; ++jj) lcj[jj] = llj[cur][cl[jj]];
#pragma unroll
            for (int ii = 0; ii < 4; ++ii) {
                int rl = wr * 64 + ii * 16 + q * 4;
                int lri[4]; float si4[4];
#pragma unroll
                for (int r = 0; r < 4; ++r) { lri[r] = lli[cur][rl + r]; si4[r] = sqi[cur][rl + r]; }
#pragma unroll
                for (int jj = 0; jj < 4; ++jj)
#pragma unroll
                    for (int r = 0; r < 4; ++r) {
                        float d2 = fmaf(-2.0f, acc[ii][jj][r], si4[r] + sj[jj]);
                        float dd = fast_sqrt(fmaxf(d2, FEPS));
                        float e = exp2f(fmaf(dd, -L2E, L2E));
                        bool same = (lri[r] == lcj[jj]);
                        float ep = same ? 0.0f : e;
                        rs[ii][r] += ep;
                        colsum[jj] += ep;
                        if (same) {
                            int c2 = lri[r];
                            int offv = s_offs[c2];
                            int ra = ib + rl + r - offv;
                            int rb = jb + cl[jj] - offv;
                            if (ra < rb)
                                dpair[(c2 << 16) + (ra << 8) + rb] = dd;
                        }
                    }
            }
        }

#pragma unroll
        for (int m = 1; m < 16; m <<= 1)
#pragma unroll
            for (int ii = 0; ii < 4; ++ii)
#pragma unroll
                for (int r = 0; r < 4; ++r) rs[ii][r] += __shfl_xor(rs[ii][r], m, 64);
        if (ml == 0) {
#pragma unroll
            for (int ii = 0; ii < 4; ++ii) {
                int rl = wr * 64 + ii * 16 + q * 4;
#pragma unroll
                for (int r = 0; r < 4; ++r) atomicAdd(&S[ib + rl + r], rs[ii][r]);
            }
        }
        if (!diag) {
#pragma unroll
            for (int m = 16; m < 64; m <<= 1)
#pragma unroll
                for (int jj = 0; jj < 4; ++jj) colsum[jj] += __shfl_xor(colsum[jj], m, 64);
            if (q == 0) {
#pragma unroll
                for (int jj = 0; jj < 4; ++jj)
                    atomicAdd(&S[jb + cl[jj]], colsum[jj]);
            }
        }

        if (it + 1 < nt) __syncthreads();
        bt = btn; jt = jtn;
    }
}

__global__ void pairB_kernel(const float* __restrict__ S,
                             const int* __restrict__ cnt,
                             const int* __restrict__ offs,
                             const float* __restrict__ dpair,
                             float* __restrict__ loss_sum,
                             unsigned int* __restrict__ done,
                             float* __restrict__ out) {
    __shared__ float Sg[256];
    __shared__ float redf[4];
    const int tid = threadIdx.x;
    const int w = tid >> 6, lane = tid & 63;
    const int c = blockIdx.x >> 2, q4 = blockIdx.x & 3;

    const int n = cnt[c];
    const int off = offs[c];
    const float* dbase = dpair + (c << 16);

    for (int m_ = tid; m_ < n; m_ += 256) Sg[m_] = S[off + m_];
    __syncthreads();

    float total = 0.f;
    for (int a = q4 * 4 + w; a < n; a += 16) {
        float Sa = Sg[a];
        const float* drow = dbase + (a << 8);
        for (int bb = lane; bb < n; bb += 64) {
            if (bb > a) {
                float J = __logf(Sa + Sg[bb]) + drow[bb];
                float h = fmaxf(J, 0.0f);
                total += 2.0f * h * h;
            }
        }
        if (lane == 0) {
            float J = __logf(2.0f * Sa) + 1e-8f;
            float h = fmaxf(J, 0.0f);
            total += h * h;
        }
    }
#pragma unroll
    for (int off2 = 32; off2 > 0; off2 >>= 1) total += __shfl_down(total, off2, 64);
    if (lane == 0) redf[w] = total;

    int tot2 = 0;
    if (w == 0) {
        int v = cnt[lane];
        tot2 = v * v;
#pragma unroll
        for (int o = 1; o < 64; o <<= 1) tot2 += __shfl_xor(tot2, o, 64);
    }
    __syncthreads();
    if (tid == 0) {
        atomicAdd(loss_sum, redf[0] + redf[1] + redf[2] + redf[3]);
        __threadfence();
        unsigned int t = atomicAdd(done, 1u);
        if (t == gridDim.x - 1) {
            float tot = atomicAdd(loss_sum, 0.0f);
            out[0] = tot / (2.0f * (float)tot2);
        }
    }
}

extern "C" void kernel_launch(void* const* d_in, const int* in_sizes, int n_in,
                              void* d_out, int out_size, void* d_ws, size_t ws_size,
                              hipStream_t stream) {
    const int* labels = (const int*)d_in[1];
    const float* feat = (const float*)d_in[0];

    float* ws = (float*)d_ws;
    float* S = ws + WS_S;
    int* cnt = (int*)(ws + WS_CNT);
    float* loss_sum = ws + WS_LOSS;
    unsigned int* done = (unsigned int*)(ws + WS_DONE);
    float* sq = ws + WS_SQ;
    int* offs = (int*)(ws + WS_OFFS);
    int* labs = (int*)(ws + WS_LABS);
    unsigned char* G8 = (unsigned char*)(ws + WS_G16A);
    float* dpair = ws + WS_DP;
    float* outp = (float*)d_out;

    void* args[] = {(void*)&labels, (void*)&feat, (void*)&cnt, (void*)&offs,
                    (void*)&sq, (void*)&G8, (void*)&S, (void*)&labs,
                    (void*)&loss_sum, (void*)&done, (void*)&dpair, (void*)&outp};
    hipError_t err = hipLaunchCooperativeKernel((void*)mega_kernel, dim3(NBLK),
                                                dim3(256), args, 0, stream);
    if (err != hipSuccess) {
        // fallback: proven 3-kernel path
        bucket_prep_kernel<<<NCLS * 2, 256, 0, stream>>>(labels, feat, cnt, offs, sq,
                                                         G8, S, labs, loss_sum, done);
        gemm_S<<<NBLK, 256, 0, stream>>>(G8, sq, labs, offs, S, dpair);
        pairB_kernel<<<NCLS * 4, 256, 0, stream>>>(S, cnt, offs, dpair, loss_sum,
                                                   done, outp);
    }
}

// Round 7
// 104.730 us; speedup vs baseline: 4.3863x; 4.3863x over previous
//
#include <hip/hip_runtime.h>

#define NPTS 8192
#define DIM  128
#define NCLS 64
#define NT   64
#define NTILES (NT * (NT + 1) / 2)   // 2080 triangular tiles
#define NBLK2 (NTILES * 2)           // 4160 col-half blocks
#define FEPS 1e-16f
#define L2E  1.442695041f

// ws layout (float elements). Kernels init all state (no host memset).
#define WS_S     0          // 8192 floats: S_i (sorted order)
#define WS_CNT   8192       // 64 ints
#define WS_LOSS  8256       // 1 float
#define WS_DONE  8257       // 1 uint
#define WS_SQ    8258       // 8192 floats (sorted order)
#define WS_OFFS  16450      // 64 ints: class start offsets
#define WS_LABS  24642      // 8192 ints: sorted-order labels
#define WS_G16A  32836      // 16B aligned; 1MB fp8 = 262144 floats
#define WS_DP    294980     // fixed-stride dpair: class c at (c<<16), row stride 256

typedef float f32x4 __attribute__((ext_vector_type(4)));

__device__ inline float fast_sqrt(float x) {
    float r;
    asm("v_sqrt_f32 %0, %1" : "=v"(r) : "v"(x));
    return r;
}

// anti-diagonal tile decode: all tiles with distance d=jt-bt precede d+1.
__device__ inline void tile_decode(int p, int& bt, int& jt) {
    int d = (int)((129.0f - fast_sqrt((float)(16641 - 8 * p))) * 0.5f);
    if (d < 0) d = 0; if (d > 63) d = 63;
    while (d > 0 && (d * 64 - ((d * (d - 1)) >> 1)) > p) --d;
    while (((d + 1) * 64 - (((d + 1) * d) >> 1)) <= p) ++d;
    bt = p - (d * 64 - ((d * (d - 1)) >> 1));
    jt = bt + d;
}

// ---- node 1+2 fused: bucketing + fp8 prep, 128 blocks (2 per class) ----
__global__ void bucket_prep_kernel(const int* __restrict__ labels,
                                   const float* __restrict__ feat,
                                   int* __restrict__ cnt,
                                   int* __restrict__ offs,
                                   float* __restrict__ sq,
                                   unsigned char* __restrict__ G,
                                   float* __restrict__ S,
                                   int* __restrict__ labs,
                                   float* __restrict__ loss_sum,
                                   unsigned int* __restrict__ done) {
    __shared__ int llab[NPTS];          // 32 KB
    __shared__ int plist[256];          // class point indices (n_c << 256)
    __shared__ int wsum[4], wless[4];
    const int tid = threadIdx.x;
    const int w = tid >> 6, lane = tid & 63;
    const int c = blockIdx.x >> 1, half = blockIdx.x & 1;

    {
        const uint4* L4 = (const uint4*)labels;
        uint4* S4 = (uint4*)llab;
#pragma unroll
        for (int k = 0; k < 8; ++k) S4[k * 256 + tid] = L4[k * 256 + tid];
    }
    if (blockIdx.x == 0 && tid == 0) { loss_sum[0] = 0.0f; done[0] = 0u; }
    __syncthreads();

    int ce = 0, clt = 0;
#pragma unroll
    for (int k = 0; k < 32; ++k) {
        int l = llab[tid + 256 * k];
        ce += (l == c) ? 1 : 0;
        clt += (l < c) ? 1 : 0;
    }
    int incl = ce;
#pragma unroll
    for (int o = 1; o < 64; o <<= 1) {
        int t1 = __shfl_up(incl, o, 64);
        if (lane >= o) incl += t1;
    }
    if (lane == 63) wsum[w] = incl;
    int t = clt;
#pragma unroll
    for (int o = 1; o < 64; o <<= 1) t += __shfl_xor(t, o, 64);
    if (lane == 0) wless[w] = t;
    __syncthreads();

    int wpre = 0;
#pragma unroll
    for (int ww = 0; ww < 4; ++ww) if (ww < w) wpre += wsum[ww];
    const int offc = wless[0] + wless[1] + wless[2] + wless[3];   // class base
    const int n = wsum[0] + wsum[1] + wsum[2] + wsum[3];          // class size

    int r = wpre + incl - ce;
#pragma unroll
    for (int k = 0; k < 32; ++k) {
        int idx = tid + 256 * k;
        if (llab[idx] == c) { plist[r] = idx; ++r; }
    }
    if (half == 0 && tid == 0) { cnt[c] = n; offs[c] = offc; }
    __syncthreads();   // plist visible

    const int mid = (n + 1) >> 1;
    const int lo = half ? mid : 0;
    const int hi = half ? n : mid;

    for (int m = lo + tid; m < hi; m += 256) { S[offc + m] = 0.0f; labs[offc + m] = c; }

    const int kl = lane & 31;
    const int rloc = lane >> 5;
    for (int base = lo; base < hi; base += 8) {
        int m = base + w * 2 + rloc;
        if (m < hi) {
            int i = plist[m];
            int sp = offc + m;
            float4 v = ((const float4*)(feat + (size_t)i * DIM))[kl];
            unsigned lo8 = (unsigned)__builtin_amdgcn_cvt_pk_fp8_f32(v.x, v.y, 0, false) & 0xffffu;
            unsigned hi8 = (unsigned)__builtin_amdgcn_cvt_pk_fp8_f32(v.z, v.w, 0, false);
            unsigned word = lo8 | (hi8 << 16);
            int tt = sp >> 7, mm = sp & 127;
            int cc = kl >> 1, pos = (kl & 1) * 4;
            *(unsigned*)&G[(size_t)tt * 16384 + cc * 1024 + mm * 8 + pos] = word;
            float s = v.x * v.x + v.y * v.y + v.z * v.z + v.w * v.w;
#pragma unroll
            for (int msk = 1; msk <= 16; msk <<= 1) s += __shfl_xor(s, msk, 64);
            if (kl == 0) sq[sp] = s;
        }
    }
}

// ---- node 3: triangular N^2 pass, 128x64 col-half tiles ----
// Block p2 = 2*tp + h handles rows of tile bt x cols [64h,64h+64) of tile jt.
// acc[2][4] = 32 AGPRs (was 64) -> regs ~96/wave -> 5 blocks/CU (was 4).
// LDS 24.5 KB: A tile 16 KB + B half 8 KB. Finer grain also halves the
// drain tail (4160 blocks over ~1280 slots). Heavy (d<=1) tiles occupy
// block ids 0..253 -> dispersed. One barrier per block (round-1 flow).
__launch_bounds__(256, 5)
__global__ void gemm_S(const unsigned char* __restrict__ Gb,
                       const float* __restrict__ sq,
                       const int* __restrict__ labs,
                       const int* __restrict__ offs,
                       float* __restrict__ S,
                       float* __restrict__ dpair) {
    const int p2 = blockIdx.x;
    const int h = p2 & 1;
    int bt, jt;
    tile_decode(p2 >> 1, bt, jt);

    __shared__ __align__(16) unsigned char ldsA[16384];   // full A tile
    __shared__ __align__(16) unsigned char ldsB[8192];    // B col-half
    __shared__ float sqi[128], sqj[64];
    __shared__ int lli[128], llj[64];
    __shared__ int s_offs[NCLS];

    const int tid = threadIdx.x;
    const int w = tid >> 6, lane = tid & 63;
    const int q = lane >> 4, ml = lane & 15;
    const int ib = bt * 128, jb = jt * 128 + 64 * h;
    const bool diag = (bt == jt);

    // stage A (16 KB) + B half (8 KB) via global_load_lds
    {
        const unsigned char* gA = Gb + (size_t)bt * 16384;
        const unsigned char* gB = Gb + (size_t)jt * 16384;
        const int wb = w << 10;          // wave-uniform 1KB base per step
        const int lb = lane << 4;
#pragma unroll
        for (int k = 0; k < 4; ++k)
            __builtin_amdgcn_global_load_lds(
                (const __attribute__((address_space(1))) unsigned int*)(gA + (k << 12) + wb + lb),
                (__attribute__((address_space(3))) unsigned int*)(ldsA + (k << 12) + wb),
                16, 0, 0);
        // B half: 512 x 16B; i = (w+4k)*64+lane; chunk c=i>>5 (1KB src stride),
        // 512B col-half offset, 16B within
#pragma unroll
        for (int k = 0; k < 2; ++k) {
            const int g = w + 4 * k;                   // 0..7
            const int i = g * 64 + lane;
            const int c = i >> 5;
            __builtin_amdgcn_global_load_lds(
                (const __attribute__((address_space(1))) unsigned int*)
                    (gB + c * 1024 + 512 * h + (i & 31) * 16),
                (__attribute__((address_space(3))) unsigned int*)(ldsB + (g << 10)),
                16, 0, 0);
        }
    }

    if (tid < 128) {
        sqi[tid] = sq[ib + tid]; lli[tid] = labs[ib + tid];
    } else if (tid < 192) {
        sqj[tid - 128] = sq[jb + tid - 128];
    } else {
        llj[tid - 192] = labs[jb + tid - 192];
    }
    if (w == 0) s_offs[lane] = offs[lane];

    __syncthreads();   // staging vmcnt + meta + offs

    const bool boundary = diag || (lli[127] == llj[0]);   // sorted: overlap iff edges match

    const long* A8 = (const long*)ldsA;
    const long* B8 = (const long*)ldsB;

    f32x4 acc[2][4];
#pragma unroll
    for (int a = 0; a < 2; ++a)
#pragma unroll
        for (int b = 0; b < 4; ++b) acc[a][b] = (f32x4){0.f, 0.f, 0.f, 0.f};

#pragma unroll
    for (int s = 0; s < 4; ++s) {
        long af[2], bf[4];
        const int kc = s * 4 + q;                 // k-chunk 0..15
        const int kbA = kc * 128, kbB = kc * 64;
#pragma unroll
        for (int ii = 0; ii < 2; ++ii) af[ii] = A8[kbA + w * 32 + ii * 16 + ml];
#pragma unroll
        for (int jj = 0; jj < 4; ++jj) bf[jj] = B8[kbB + jj * 16 + ml];
#pragma unroll
        for (int ii = 0; ii < 2; ++ii)
#pragma unroll
            for (int jj = 0; jj < 4; ++jj)
                acc[ii][jj] = __builtin_amdgcn_mfma_f32_16x16x32_fp8_fp8(af[ii], bf[jj], acc[ii][jj], 0, 0, 0);
    }

    int cl[4]; float sj[4];
#pragma unroll
    for (int jj = 0; jj < 4; ++jj) {
        cl[jj] = jj * 16 + ml;                    // local col in half
        sj[jj] = sqj[cl[jj]];
    }
    float rs[2][4];
#pragma unroll
    for (int a = 0; a < 2; ++a)
#pragma unroll
        for (int r = 0; r < 4; ++r) rs[a][r] = 0.0f;
    float colsum[4] = {0.f, 0.f, 0.f, 0.f};

    if (!boundary) {
        // lean epilogue: no same-label pairs possible here
#pragma unroll
        for (int ii = 0; ii < 2; ++ii) {
            int rl = w * 32 + ii * 16 + q * 4;
            float si4[4];
#pragma unroll
            for (int r = 0; r < 4; ++r) si4[r] = sqi[rl + r];
#pragma unroll
            for (int jj = 0; jj < 4; ++jj)
#pragma unroll
                for (int r = 0; r < 4; ++r) {
                    float d2 = fmaf(-2.0f, acc[ii][jj][r], si4[r] + sj[jj]);
                    float dd = fast_sqrt(fmaxf(d2, FEPS));
                    float e = exp2f(fmaf(dd, -L2E, L2E));
                    rs[ii][r] += e;
                    colsum[jj] += e;
                }
        }
    } else {
        // full epilogue: label predicate + canonical dpair writes
        int lcj[4];
#pragma unroll
        for (int jj = 0; jj < 4; ++jj) lcj[jj] = llj[cl[jj]];
#pragma unroll
        for (int ii = 0; ii < 2; ++ii) {
            int rl = w * 32 + ii * 16 + q * 4;
            int lri[4]; float si4[4];
#pragma unroll
            for (int r = 0; r < 4; ++r) { lri[r] = lli[rl + r]; si4[r] = sqi[rl + r]; }
#pragma unroll
            for (int jj = 0; jj < 4; ++jj)
#pragma unroll
                for (int r = 0; r < 4; ++r) {
                    float d2 = fmaf(-2.0f, acc[ii][jj][r], si4[r] + sj[jj]);
                    float dd = fast_sqrt(fmaxf(d2, FEPS));
                    float e = exp2f(fmaf(dd, -L2E, L2E));
                    bool same = (lri[r] == lcj[jj]);
                    float ep = same ? 0.0f : e;
                    rs[ii][r] += ep;
                    colsum[jj] += ep;
                    if (same) {
                        int c2 = lri[r];
                        int offv = s_offs[c2];
                        int ra = ib + rl + r - offv;
                        int rb = jb + cl[jj] - offv;
                        if (ra < rb)
                            dpair[(c2 << 16) + (ra << 8) + rb] = dd;  // fixed stride 256
                    }
                }
        }
    }

    // hoisted reduces: 8 independent depth-4 chains, pipelined
#pragma unroll
    for (int m = 1; m < 16; m <<= 1)
#pragma unroll
        for (int ii = 0; ii < 2; ++ii)
#pragma unroll
            for (int r = 0; r < 4; ++r) rs[ii][r] += __shfl_xor(rs[ii][r], m, 64);
    if (ml == 0) {
#pragma unroll
        for (int ii = 0; ii < 2; ++ii) {
            int rl = w * 32 + ii * 16 + q * 4;
#pragma unroll
            for (int r = 0; r < 4; ++r) atomicAdd(&S[ib + rl + r], rs[ii][r]);
        }
    }
    if (!diag) {    // diag halves: every ordered pair counted via rows
#pragma unroll
        for (int m = 16; m < 64; m <<= 1)
#pragma unroll
            for (int jj = 0; jj < 4; ++jj) colsum[jj] += __shfl_xor(colsum[jj], m, 64);
        if (q == 0) {
#pragma unroll
            for (int jj = 0; jj < 4; ++jj)
                atomicAdd(&S[jb + cl[jj]], colsum[jj]);
        }
    }
}

// ---- node 4: per-class loss, 4 blocks/class, contiguous S + coalesced dpair rows ----
__global__ void pairB_kernel(const float* __restrict__ S,
                             const int* __restrict__ cnt,
                             const int* __restrict__ offs,
                             const float* __restrict__ dpair,
                             float* __restrict__ loss_sum,
                             unsigned int* __restrict__ done,
                             float* __restrict__ out) {
    __shared__ float Sg[256];
    __shared__ float redf[4];
    const int tid = threadIdx.x;
    const int w = tid >> 6, lane = tid & 63;
    const int c = blockIdx.x >> 2, q4 = blockIdx.x & 3;

    const int n = cnt[c];                 // uniform scalar loads (no scan)
    const int off = offs[c];
    const float* dbase = dpair + (c << 16);

    for (int m_ = tid; m_ < n; m_ += 256) Sg[m_] = S[off + m_];   // contiguous
    __syncthreads();

    float total = 0.f;
    for (int a = q4 * 4 + w; a < n; a += 16) {   // 16 row-streams across 4 blocks
        float Sa = Sg[a];
        const float* drow = dbase + (a << 8);
        for (int bb = lane; bb < n; bb += 64) {
            if (bb > a) {
                float J = __logf(Sa + Sg[bb]) + drow[bb];   // coalesced upper-tri read
                float h = fmaxf(J, 0.0f);
                total += 2.0f * h * h;                      // symmetry
            }
        }
        if (lane == 0) {                                    // diagonal: d = sqrt(EPS)
            float J = __logf(2.0f * Sa) + 1e-8f;
            float h = fmaxf(J, 0.0f);
            total += h * h;
        }
    }
#pragma unroll
    for (int off2 = 32; off2 > 0; off2 >>= 1) total += __shfl_down(total, off2, 64);
    if (lane == 0) redf[w] = total;

    int tot2 = 0;
    if (w == 0) {
        int v = cnt[lane];
        tot2 = v * v;
#pragma unroll
        for (int o = 1; o < 64; o <<= 1) tot2 += __shfl_xor(tot2, o, 64);
    }
    __syncthreads();
    if (tid == 0) {
        atomicAdd(loss_sum, redf[0] + redf[1] + redf[2] + redf[3]);
        __threadfence();
        unsigned int t = atomicAdd(done, 1u);
        if (t == gridDim.x - 1) {
            float tot = atomicAdd(loss_sum, 0.0f);
            out[0] = tot / (2.0f * (float)tot2);
        }
    }
}

extern "C" void kernel_launch(void* const* d_in, const int* in_sizes, int n_in,
                              void* d_out, int out_size, void* d_ws, size_t ws_size,
                              hipStream_t stream) {
    const float* feat = (const float*)d_in[0];
    const int* labels = (const int*)d_in[1];

    float* ws = (float*)d_ws;
    float* S = ws + WS_S;
    int* cnt = (int*)(ws + WS_CNT);
    float* loss_sum = ws + WS_LOSS;
    unsigned int* done = (unsigned int*)(ws + WS_DONE);
    float* sq = ws + WS_SQ;
    int* offs = (int*)(ws + WS_OFFS);
    int* labs = (int*)(ws + WS_LABS);
    unsigned char* G8 = (unsigned char*)(ws + WS_G16A);
    float* dpair = ws + WS_DP;
    float* outp = (float*)d_out;

    bucket_prep_kernel<<<NCLS * 2, 256, 0, stream>>>(labels, feat, cnt, offs, sq, G8,
                                                     S, labs, loss_sum, done);        // node 1+2
    gemm_S<<<NBLK2, 256, 0, stream>>>(G8, sq, labs, offs, S, dpair);                  // node 3
    pairB_kernel<<<NCLS * 4, 256, 0, stream>>>(S, cnt, offs, dpair, loss_sum,
                                               done, outp);                           // node 4
}